// Round 9
// baseline (4266.696 us; speedup 1.0000x reference)
//
#include <hip/hip_runtime.h>

using u16 = unsigned short;
using u32 = unsigned int;

typedef __attribute__((ext_vector_type(8))) short bf16x8;
typedef __attribute__((ext_vector_type(4))) float f32x4;

#define L2E 1.44269504f

__device__ __forceinline__ float bf2f(u16 u) {
  union { u32 i; float f; } v; v.i = ((u32)u) << 16; return v.f;
}
__device__ __forceinline__ u16 f2bf(float f) {
  union { float f; u32 i; } v; v.f = f;
  u32 i = v.i;
  return (u16)((i + 0x7FFFu + ((i >> 16) & 1u)) >> 16);
}
__device__ __forceinline__ float fexp2(float x) { float r; asm("v_exp_f32 %0, %1" : "=v"(r) : "v"(x)); return r; }
__device__ __forceinline__ float frcp(float x) { float r; asm("v_rcp_f32 %0, %1" : "=v"(r) : "v"(x)); return r; }
__device__ __forceinline__ float sig_s(float xp) { return frcp(1.0f + fexp2(-xp)); }      // x pre-scaled by log2e
__device__ __forceinline__ float tanh_s(float x2) { return fmaf(-2.0f, frcp(1.0f + fexp2(x2)), 1.0f); } // x pre-scaled by 2log2e

__device__ __forceinline__ void barrier_lgkm() {
  asm volatile("s_waitcnt lgkmcnt(0)\n\ts_barrier" ::: "memory");
}

__device__ __forceinline__ float ldin(const void* p, long i, int f32) {
  return f32 ? ((const float*)p)[i] : bf2f(((const u16*)p)[i]);
}
__device__ __forceinline__ bf16x8 ldfrag(const void* p, long i, int f32) {
  if (!f32) return *(const bf16x8*)((const u16*)p + i);
  const float* f = (const float*)p + i;
  bf16x8 r;
#pragma unroll
  for (int j = 0; j < 8; ++j) r[j] = (short)f2bf(f[j]);
  return r;
}
__device__ __forceinline__ bf16x8 ldfrag_s(const void* p, long i, int f32, float s) {
  bf16x8 r;
  if (!f32) {
    const u16* h = (const u16*)p + i;
#pragma unroll
    for (int j = 0; j < 8; ++j) r[j] = (short)f2bf(bf2f(h[j]) * s);
  } else {
    const float* f = (const float*)p + i;
#pragma unroll
    for (int j = 0; j < 8; ++j) r[j] = (short)f2bf(f[j] * s);
  }
  return r;
}
__device__ __forceinline__ uint2 ld4(const void* p, long i, int f32) {
  if (!f32) return *(const uint2*)((const u16*)p + i);
  const float* f = (const float*)p + i;
  return make_uint2((u32)f2bf(f[0]) | ((u32)f2bf(f[1]) << 16),
                    (u32)f2bf(f[2]) | ((u32)f2bf(f[3]) << 16));
}

// inline dtype probe: ff_w ~ N(0,0.05^2) -> bf16 decodes all sane; f32-as-u16 doesn't
__device__ __forceinline__ int dtype_probe(const void* ffw) {
  const u16* h = (const u16*)ffw;
  int sane = 0;
  for (int i = 0; i < 64; ++i) {
    float v = bf2f(h[i]);
    sane += (v == v && fabsf(v) <= 1.0f) ? 1 : 0;
  }
  return (sane >= 60) ? 0 : 1;
}

// ---------------- prep ----------------
__global__ void prep_k(const void* ffw, const void* ffb,
                       const void* wih0f, const void* bih0f, const void* bhh0f,
                       const void* wih0b, const void* bih0b, const void* bhh0b,
                       const void* bih1f, const void* bhh1f,
                       const void* bih1b, const void* bhh1b,
                       float* __restrict__ prep0, float* __restrict__ bias1) {
  const int f32 = dtype_probe(ffw);
  int dir = blockIdx.x, r = threadIdx.x;
  const void* wih  = dir ? wih0b : wih0f;
  const void* bih0 = dir ? bih0b : bih0f;
  const void* bhh0 = dir ? bhh0b : bhh0f;
  const void* bih1 = dir ? bih1b : bih1f;
  const void* bhh1 = dir ? bhh1b : bhh1f;
  float u = 0.f, v = 0.f;
  for (int k = 0; k < 128; ++k) {
    float wv = ldin(wih, r * 128 + k, f32);
    u += wv * ldin(ffw, k, f32);
    v += wv * ldin(ffb, k, f32);
  }
  const float sc = ((r >> 7) == 2) ? 2.0f * L2E : L2E;
  float bi = ldin(bih0, r, f32) + ldin(bhh0, r, f32);
  prep0[dir * 1536 + r]        = u * sc;
  prep0[dir * 1536 + 512 + r]  = (bi + v) * sc;
  prep0[dir * 1536 + 1024 + r] = bi * sc;
  bias1[dir * 512 + r] = (ldin(bih1, r, f32) + ldin(bhh1, r, f32)) * sc;
}

// ---------------- conv body: sub-block s (0/1), vtid 0..511 ----------------
__device__ void conv_body(int blk, int s, int tid, const void* x,
                          const void* cw0, const void* cb0, const void* cw1, const void* cb1,
                          const void* cw2, const void* cb2, const void* cw3, const void* cb3,
                          int f32, float* __restrict__ pcavg) {
  int b = blk >> 3, ck = blk & 7;
  int P = ck * 255;
  __shared__ float xs[2][264];
  __shared__ float c1s[2][4][264];
  __shared__ float c2s[2][8][264];
  __shared__ float w0s[2][12], w1s[2][96], w2s[2][384], w3s[2][4608];
  __shared__ float b0s[2][4], b1s[2][8], b2s[2][16], b3s[2][96];
  __shared__ float red[2][8][96];
  for (int i = tid; i < 263; i += 512) xs[s][i] = ldin(x, (long)b * 2048 + P + i, f32);
  for (int i = tid; i < 12; i += 512) w0s[s][i] = ldin(cw0, i, f32);
  for (int i = tid; i < 96; i += 512) w1s[s][i] = ldin(cw1, i, f32);
  for (int i = tid; i < 384; i += 512) w2s[s][i] = ldin(cw2, i, f32);
  for (int i = tid; i < 4608; i += 512) w3s[s][i] = ldin(cw3, i, f32);
  if (tid < 4) b0s[s][tid] = ldin(cb0, tid, f32);
  if (tid < 8) b1s[s][tid] = ldin(cb1, tid, f32);
  if (tid < 16) b2s[s][tid] = ldin(cb2, tid, f32);
  if (tid < 96) b3s[s][tid] = ldin(cb3, tid, f32);
  __syncthreads();
  for (int i = tid; i < 4 * 261; i += 512) {
    int ch = i / 261, t = i % 261;
    float v = b0s[s][ch];
#pragma unroll
    for (int d = 0; d < 3; ++d) v += w0s[s][ch * 3 + d] * xs[s][t + d];
    c1s[s][ch][t] = fmaxf(v, 0.f);
  }
  __syncthreads();
  for (int i = tid; i < 8 * 259; i += 512) {
    int ch = i / 259, t = i % 259;
    float v = b1s[s][ch];
    for (int ic = 0; ic < 4; ++ic)
#pragma unroll
      for (int d = 0; d < 3; ++d) v += w1s[s][(ch * 4 + ic) * 3 + d] * c1s[s][ic][t + d];
    c2s[s][ch][t] = fmaxf(v, 0.f);
  }
  __syncthreads();
  const bool act = tid < 255;
  float c3w[16][3];
#pragma unroll
  for (int m = 0; m < 16; ++m)
#pragma unroll
    for (int dt = 0; dt < 3; ++dt) c3w[m][dt] = 0.f;
  if (act) {
#pragma unroll
    for (int m = 0; m < 16; ++m)
#pragma unroll
      for (int dt = 0; dt < 3; ++dt) {
        float v = b2s[s][m];
        for (int ic = 0; ic < 8; ++ic)
#pragma unroll
          for (int d = 0; d < 3; ++d) v += w2s[s][(m * 8 + ic) * 3 + d] * c2s[s][ic][tid + dt + d];
        c3w[m][dt] = fmaxf(v, 0.f);
      }
  }
  int wv = tid >> 6, lane = tid & 63;
  for (int o = 0; o < 96; ++o) {
    float v = b3s[s][o];
#pragma unroll
    for (int m = 0; m < 16; ++m)
#pragma unroll
      for (int dt = 0; dt < 3; ++dt) v += w3s[s][(o * 16 + m) * 3 + dt] * c3w[m][dt];
    float vr = act ? fmaxf(v, 0.f) : 0.f;
    for (int off = 32; off > 0; off >>= 1) vr += __shfl_down(vr, off, 64);
    if (lane == 0) red[s][wv][o] = vr;
  }
  __syncthreads();
  if (tid < 96) {
    float v = 0.f;
#pragma unroll
    for (int k = 0; k < 8; ++k) v += red[s][k][tid];
    pcavg[(size_t)(b * 8 + ck) * 96 + tid] = v;
  }
}

// ---------------- layer-1 input GEMM body: sub-block s, vtid ----------------
__device__ void xg_gemm_body(int bi, int s, int tid,
                             const void* wih1f, const void* wih1b,
                             const float* __restrict__ bias1,
                             const u16* __restrict__ f0, const u16* __restrict__ r0,
                             const int* __restrict__ lengths,
                             u16* __restrict__ xg_wr, int ct0, int tc, int f32) {
  const int TCB = 32;
  int nt = tc / TCB;
  int dir = bi / (4 * nt);
  int rem = bi % (4 * nt);
  int g = rem / nt, tcb = rem % nt;
  int tstart = ct0 + tcb * TCB;
  const int w = tid >> 6, lane = tid & 63, q = lane >> 4, col = lane & 15;

  const void* wih = dir ? wih1b : wih1f;
  bf16x8 af[4][8];
#pragma unroll
  for (int gt = 0; gt < 4; ++gt)
#pragma unroll
    for (int kt = 0; kt < 8; ++kt)
      af[gt][kt] = ldfrag(wih, (long)(gt * 128 + w * 16 + col) * 256 + kt * 32 + q * 8, f32);
  f32x4 bias4[4];
#pragma unroll
  for (int gt = 0; gt < 4; ++gt)
    bias4[gt] = *(const f32x4*)(bias1 + dir * 512 + gt * 128 + w * 16 + q * 4);

  __shared__ u16 bin[2][2][16][264];
  int sb = tid >> 5, sk = (tid & 31) * 8;
  int gb = g * 16 + sb;
  int len_s = lengths[gb];

  auto stage = [&](int t, int buf) {
    uint4 v = make_uint4(0u, 0u, 0u, 0u);
    if (t < len_s) {
      int qt = len_s - 1 - t; if (qt < 0) qt = 0;
      int th0 = dir ? qt : t;
      int th1 = dir ? t : qt;
      if (sk < 128)
        v = *(const uint4*)(f0 + ((size_t)th0 * 64 + gb) * 128 + sk);
      else
        v = *(const uint4*)(r0 + ((size_t)th1 * 64 + gb) * 128 + sk - 128);
    }
    *(uint4*)&bin[s][buf][sb][sk] = v;
  };
  stage(tstart, 0);
  const int bglob = g * 16 + col;
  const int G4o = bglob >> 2, c4g = bglob & 3;
  for (int i = 0; i < TCB; ++i) {
    int t = tstart + i, buf = i & 1;
    barrier_lgkm();
    if (i + 1 < TCB) stage(t + 1, buf ^ 1);
    bf16x8 bfr[8];
#pragma unroll
    for (int kt = 0; kt < 8; ++kt) bfr[kt] = *(const bf16x8*)(&bin[s][buf][col][kt * 32 + q * 8]);
    f32x4 acc[4];
#pragma unroll
    for (int gt = 0; gt < 4; ++gt) acc[gt] = (f32x4){0.f, 0.f, 0.f, 0.f};
#pragma unroll
    for (int kt = 0; kt < 8; ++kt)
#pragma unroll
      for (int gt = 0; gt < 4; ++gt)
        acc[gt] = __builtin_amdgcn_mfma_f32_16x16x32_bf16(af[gt][kt], bfr[kt], acc[gt], 0, 0, 0);
    size_t eb = ((((size_t)(t - ct0) * 2 + dir) * 16 + G4o) * 8 + w) * 256 + q * 64 + c4g * 4;
#pragma unroll
    for (int gt = 0; gt < 4; ++gt) {
      float sgt = (gt == 2) ? 2.0f * L2E : L2E;
#pragma unroll
      for (int r = 0; r < 4; ++r)
        xg_wr[eb + r * 16 + gt] = f2bf(fmaf(acc[gt][r], sgt, bias4[gt][r]));
    }
  }
}

// ---------------- fused: L0 scan (blocks 0..15, 2 sequences each) + conv (blocks 16..271) ----------------
__global__ __launch_bounds__(1024, 1) void scan0_conv(
    const void* whhf, const void* whhb,
    const void* x, const float* __restrict__ prep0,
    const int* __restrict__ lengths,
    u16* __restrict__ outf, u16* __restrict__ outr,
    const void* cw0, const void* cb0, const void* cw1, const void* cb1,
    const void* cw2, const void* cb2, const void* cw3, const void* cb3,
    float* __restrict__ pcavg, const void* ffw) {
  const int f32 = dtype_probe(ffw);
  const int tid = threadIdx.x;
  const int seq = tid >> 9, vtid = tid & 511;
  if (blockIdx.x >= 16) {
    conv_body((blockIdx.x - 16) * 2 + seq, seq, vtid,
              x, cw0, cb0, cw1, cb1, cw2, cb2, cw3, cb3, f32, pcavg);
    return;
  }
  const int vblk = blockIdx.x * 2 + seq;
  const int dir = vblk >> 4, G4 = vblk & 15;
  const int w = vtid >> 6, lane = vtid & 63, q = lane >> 4, col = lane & 15;
  const int c4 = lane & 3, uu_ = lane >> 2;
  const int unit = w * 16 + uu_;
  const int b = G4 * 4 + c4;
  const bool jb1 = ((lane >> 2) & 1) != 0;
  const bool jb2 = ((lane >> 2) & 2) != 0;

  __shared__ u16 hbuf[2][2][4][160];
  __shared__ u16 xls[2][4 * 2056];

  const void* whh = dir ? whhb : whhf;
  bf16x8 afr[4][4];
#pragma unroll
  for (int gt = 0; gt < 4; ++gt) {
    float sgt = (gt == 2) ? 2.0f * L2E : L2E;
#pragma unroll
    for (int kt = 0; kt < 4; ++kt)
      afr[gt][kt] = ldfrag_s(whh, (long)(gt * 128 + w * 16 + col) * 128 + kt * 32 + q * 8, f32, sgt);
  }

  float uuc[4], ppc[4], bbc[4];
  {
    const float* pr = prep0 + dir * 1536;
#pragma unroll
    for (int gt = 0; gt < 4; ++gt) {
      int rb = gt * 128 + unit;
      uuc[gt] = pr[rb];
      ppc[gt] = pr[512 + rb];
      bbc[gt] = pr[1024 + rb];
    }
  }
  const int len_c = lengths[b];
  const int lm1 = dir ? (len_c - 1) : 0;
  const int sgn = dir ? -1 : 1;

  float cst = 0.f;
  hbuf[seq][0][c4][unit] = 0; hbuf[seq][1][c4][unit] = 0;
  for (int i = vtid; i < 4 * 512; i += 512) {
    int row = i >> 9, t4 = (i & 511) * 4;
    *(uint2*)&xls[seq][row * 2056 + t4] = ld4(x, (long)(G4 * 4 + row) * 2048 + t4, f32);
  }
  __syncthreads();

  const u16* xbase = &xls[seq][c4 * 2056];
  auto mkpre = [&](int t, float* pre) {
    int tb = lm1 + sgn * t;
    tb = tb < 0 ? 0 : tb;
    float xv = bf2f(xbase[tb]);
    bool valid = t < len_c;
    float xvv = valid ? xv : 0.f;
#pragma unroll
    for (int gt = 0; gt < 4; ++gt)
      pre[gt] = fmaf(xvv, uuc[gt], valid ? ppc[gt] : bbc[gt]);
  };
  float pre[4];
  mkpre(0, pre);

  int p = 0;
  u16* outp = (dir ? outr : outf) + (size_t)b * 128 + unit;   // advance 8192/step
  for (int t = 0; t < 2048; ++t) {
    bf16x8 bfr[4];
#pragma unroll
    for (int kt = 0; kt < 4; ++kt) bfr[kt] = *(const bf16x8*)(&hbuf[seq][p][col & 3][kt * 32 + q * 8]);

    f32x4 acc[4];
#pragma unroll
    for (int gt = 0; gt < 4; ++gt) acc[gt] = (f32x4){0.f, 0.f, 0.f, 0.f};
#pragma unroll
    for (int kt = 0; kt < 4; ++kt)
#pragma unroll
      for (int gt = 0; gt < 4; ++gt)
        acc[gt] = __builtin_amdgcn_mfma_f32_16x16x32_bf16(afr[gt][kt], bfr[kt], acc[gt], 0, 0, 0);

    float gv[4];
#pragma unroll
    for (int gt = 0; gt < 4; ++gt) {
      float a = jb2 ? acc[gt][2] : acc[gt][0];
      float c = jb2 ? acc[gt][3] : acc[gt][1];
      gv[gt] = (jb1 ? c : a) + pre[gt];
    }

    float sf = sig_s(gv[1]);
    float si = sig_s(gv[0]);
    float tg = tanh_s(gv[2]);
    float so = sig_s(gv[3]);
    float cs = fmaf(sf, cst, si * tg);
    cst = cs;
    float hv = so * tanh_s(cs * (2.0f * L2E));
    u16 hb = f2bf(hv);
    hbuf[seq][p ^ 1][c4][unit] = hb;
    *outp = hb;
    outp += 8192;
    mkpre(t + 1, pre);
    barrier_lgkm();
    p ^= 1;
  }
}

// ---------------- fused: L1 scan chunk (blocks 0..15, 2 seq each) + xg_gemm for NEXT chunk ----------------
__global__ __launch_bounds__(1024, 1) void scan1_gemm(
    const void* whhf, const void* whhb,
    const u16* __restrict__ xg_rd, u16* __restrict__ xg_wr,
    const void* wih1f, const void* wih1b, const float* __restrict__ bias1,
    const u16* __restrict__ f0, const u16* __restrict__ r0,
    const int* __restrict__ lengths,
    float* __restrict__ cstate, u16* __restrict__ hstate,
    float* __restrict__ pacc, float* __restrict__ hfeat,
    const void* ffw, int t0, int t1, int gct0, int TCc) {
  const int f32 = dtype_probe(ffw);
  const int tid = threadIdx.x;
  const int seq = tid >> 9, vtid = tid & 511;
  if (blockIdx.x >= 16) {
    xg_gemm_body((blockIdx.x - 16) * 2 + seq, seq, vtid,
                 wih1f, wih1b, bias1, f0, r0, lengths, xg_wr, gct0, TCc, f32);
    return;
  }
  const int vblk = blockIdx.x * 2 + seq;
  const int dir = vblk >> 4, G4 = vblk & 15;
  const int w = vtid >> 6, lane = vtid & 63, q = lane >> 4, col = lane & 15;
  const int c4 = lane & 3, uu_ = lane >> 2;
  const int unit = w * 16 + uu_;
  const int b = G4 * 4 + c4;
  const bool jb1 = ((lane >> 2) & 1) != 0;
  const bool jb2 = ((lane >> 2) & 2) != 0;

  __shared__ u16 hbuf[2][2][4][160];

  const void* whh = dir ? whhb : whhf;
  bf16x8 afr[4][4];
#pragma unroll
  for (int gt = 0; gt < 4; ++gt) {
    float sgt = (gt == 2) ? 2.0f * L2E : L2E;
#pragma unroll
    for (int kt = 0; kt < 4; ++kt)
      afr[gt][kt] = ldfrag_s(whh, (long)(gt * 128 + w * 16 + col) * 128 + kt * 32 + q * 8, f32, sgt);
  }
  const int len_c = lengths[b];
  const int lastt = dir ? 0 : (len_c - 1);

  int p = t0 & 1;
  float cst, psum, pmax, plast;
  if (t0 == 0) {
    cst = 0.f;
    hbuf[seq][0][c4][unit] = 0; hbuf[seq][1][c4][unit] = 0;
    psum = 0.f; pmax = -1e30f; plast = 0.f;
  } else {
    cst = cstate[vblk * 512 + vtid];
    hbuf[seq][p][c4][unit] = hstate[vblk * 512 + c4 * 128 + unit];
    long pb = (long)(vblk * 512 + vtid) * 4;
    psum = pacc[pb]; pmax = pacc[pb + 1]; plast = pacc[pb + 2];
  }
  __syncthreads();

  // xg pointer walks forward 65536 elements per step (affine for LSR)
  const u16* xgp = xg_rd + (((size_t)dir * 16 + G4) * 8 + w) * 256 + (size_t)lane * 4;
  float xf[4];
  auto unpack = [&](uint2 c, float* o) {
    o[0] = bf2f((u16)(c.x & 0xffffu));
    o[1] = bf2f((u16)(c.x >> 16));
    o[2] = bf2f((u16)(c.y & 0xffffu));
    o[3] = bf2f((u16)(c.y >> 16));
  };
  uint2 nxtA, nxtB;
  {
    uint2 c0 = *(const uint2*)xgp;
    unpack(c0, xf);
    nxtA = (t0 + 1 < t1) ? *(const uint2*)(xgp + 65536) : make_uint2(0, 0);
    nxtB = (t0 + 2 < t1) ? *(const uint2*)(xgp + 2 * 65536) : make_uint2(0, 0);
    xgp += (size_t)3 * 65536;
  }

  for (int t = t0; t < t1; ++t) {
    bf16x8 bfr[4];
#pragma unroll
    for (int kt = 0; kt < 4; ++kt) bfr[kt] = *(const bf16x8*)(&hbuf[seq][p][col & 3][kt * 32 + q * 8]);

    f32x4 acc[4];
#pragma unroll
    for (int gt = 0; gt < 4; ++gt) acc[gt] = (f32x4){0.f, 0.f, 0.f, 0.f};
#pragma unroll
    for (int kt = 0; kt < 4; ++kt)
#pragma unroll
      for (int gt = 0; gt < 4; ++gt)
        acc[gt] = __builtin_amdgcn_mfma_f32_16x16x32_bf16(afr[gt][kt], bfr[kt], acc[gt], 0, 0, 0);

    float gv[4];
#pragma unroll
    for (int gt = 0; gt < 4; ++gt) {
      float a = jb2 ? acc[gt][2] : acc[gt][0];
      float c = jb2 ? acc[gt][3] : acc[gt][1];
      gv[gt] = (jb1 ? c : a) + xf[gt];
    }

    float sf = sig_s(gv[1]);
    float si = sig_s(gv[0]);
    float tg = tanh_s(gv[2]);
    float so = sig_s(gv[3]);
    float cs = fmaf(sf, cst, si * tg);
    cst = cs;
    float hv = so * tanh_s(cs * (2.0f * L2E));
    u16 hb = f2bf(hv);
    hbuf[seq][p ^ 1][c4][unit] = hb;
    bool inlen = t < len_c;
    psum += inlen ? hv : 0.f;
    pmax = fmaxf(pmax, inlen ? hv : -1e30f);
    plast = (t == lastt) ? hv : plast;
    unpack(nxtA, xf);
    nxtA = nxtB;
    if (t + 3 < t1) nxtB = *(const uint2*)xgp;
    xgp += 65536;
    barrier_lgkm();
    p ^= 1;
  }

  cstate[vblk * 512 + vtid] = cst;
  hstate[vblk * 512 + c4 * 128 + unit] = hbuf[seq][p][c4][unit];
  {
    long pb = (long)(vblk * 512 + vtid) * 4;
    pacc[pb] = psum; pacc[pb + 1] = pmax; pacc[pb + 2] = plast;
  }
  if (t1 == 2048) {
    int base = b * 768 + dir * 128 + unit;
    hfeat[base]       = psum / (float)len_c;
    hfeat[base + 256] = pmax;
    hfeat[base + 512] = plast;
  }
}

// ---------------- standalone first xg_gemm (2 tiles per block) ----------------
__global__ __launch_bounds__(1024, 1) void xg_gemm0(
    const void* wih1f, const void* wih1b, const float* __restrict__ bias1,
    const u16* __restrict__ f0, const u16* __restrict__ r0,
    const int* __restrict__ lengths,
    u16* __restrict__ xg_wr, const void* ffw, int ct0, int tc) {
  const int tid = threadIdx.x;
  xg_gemm_body(blockIdx.x * 2 + (tid >> 9), tid >> 9, tid & 511,
               wih1f, wih1b, bias1, f0, r0, lengths, xg_wr, ct0, tc, dtype_probe(ffw));
}

// ---------------- final linear ----------------
__global__ void final_k(const float* __restrict__ pcavg, const float* __restrict__ hfeat,
                        const void* lw, const void* lb,
                        const void* ffw, void* outv) {
  const int f32 = dtype_probe(ffw);
  int b = blockIdx.x, tid = threadIdx.x;
  float p0 = 0.f, p1 = 0.f, p2 = 0.f, p3 = 0.f;
  for (int k = tid; k < 864; k += 64) {
    float f;
    if (k < 96) {
      float s = 0.f;
#pragma unroll
      for (int c = 0; c < 8; ++c) s += pcavg[(size_t)(b * 8 + c) * 96 + k];
      f = s / 2040.f;
    } else {
      f = hfeat[b * 768 + k - 96];
    }
    p0 += f * ldin(lw, k, f32);
    p1 += f * ldin(lw, 864 + k, f32);
    p2 += f * ldin(lw, 2 * 864 + k, f32);
    p3 += f * ldin(lw, 3 * 864 + k, f32);
  }
  for (int off = 32; off > 0; off >>= 1) {
    p0 += __shfl_down(p0, off, 64);
    p1 += __shfl_down(p1, off, 64);
    p2 += __shfl_down(p2, off, 64);
    p3 += __shfl_down(p3, off, 64);
  }
  if (tid == 0) {
    float v0 = p0 + ldin(lb, 0, f32), v1 = p1 + ldin(lb, 1, f32);
    float v2 = p2 + ldin(lb, 2, f32), v3 = p3 + ldin(lb, 3, f32);
    if (f32) {
      float* o = (float*)outv;
      o[b * 4 + 0] = v0; o[b * 4 + 1] = v1; o[b * 4 + 2] = v2; o[b * 4 + 3] = v3;
    } else {
      u16* o = (u16*)outv;
      o[b * 4 + 0] = f2bf(v0); o[b * 4 + 1] = f2bf(v1);
      o[b * 4 + 2] = f2bf(v2); o[b * 4 + 3] = f2bf(v3);
    }
  }
}

extern "C" void kernel_launch(void* const* d_in, const int* in_sizes, int n_in,
                              void* d_out, int out_size, void* d_ws, size_t ws_size,
                              hipStream_t stream) {
  const void* x      = d_in[0];
  const int* lengths = (const int*)d_in[1];
  const void* ffw = d_in[2];
  const void* ffb = d_in[3];
  const void* wih0f = d_in[4];  const void* whh0f = d_in[5];
  const void* bih0f = d_in[6];  const void* bhh0f = d_in[7];
  const void* wih0b = d_in[8];  const void* whh0b = d_in[9];
  const void* bih0b = d_in[10]; const void* bhh0b = d_in[11];
  const void* wih1f = d_in[12]; const void* whh1f = d_in[13];
  const void* bih1f = d_in[14]; const void* bhh1f = d_in[15];
  const void* wih1b = d_in[16]; const void* whh1b = d_in[17];
  const void* bih1b = d_in[18]; const void* bhh1b = d_in[19];
  const void* cw0 = d_in[20]; const void* cb0 = d_in[21];
  const void* cw1 = d_in[22]; const void* cb1 = d_in[23];
  const void* cw2 = d_in[24]; const void* cb2 = d_in[25];
  const void* cw3 = d_in[26]; const void* cb3 = d_in[27];
  const void* lw = d_in[28];  const void* lb = d_in[29];

  float* prep0  = (float*)d_ws + 16;
  float* bias1  = prep0 + 3072;
  float* pcavg  = bias1 + 1024;
  float* hfeat  = pcavg + 49152;
  float* cstate = hfeat + 49152;
  float* pacc   = cstate + 16384;
  u16* f0 = (u16*)(pacc + 65536);
  const size_t SEQ = (size_t)2048 * 64 * 128;
  u16* r0 = f0 + SEQ;
  u16* hstate = r0 + SEQ;
  u16* xg = hstate + 16384;

  size_t base_bytes = (size_t)((char*)xg - (char*)d_ws);
  int TC = 32;
  for (int cand = 512; cand >= 32; cand >>= 1)
    if (ws_size >= base_bytes + (size_t)2 * cand * 65536 * 2) { TC = cand; break; }

  prep_k<<<2, 512, 0, stream>>>(ffw, ffb, wih0f, bih0f, bhh0f, wih0b, bih0b, bhh0b,
                                bih1f, bhh1f, bih1b, bhh1b, prep0, bias1);
  scan0_conv<<<16 + 256, 1024, 0, stream>>>(whh0f, whh0b, x, prep0, lengths, f0, r0,
                                            cw0, cb0, cw1, cb1, cw2, cb2, cw3, cb3,
                                            pcavg, ffw);
  const int nch = 2048 / TC;
  xg_gemm0<<<TC / 8, 1024, 0, stream>>>(wih1f, wih1b, bias1, f0, r0, lengths,
                                        xg, ffw, 0, TC);
  for (int ch = 0; ch < nch; ++ch) {
    u16* xg_rd = xg + (size_t)(ch & 1) * TC * 65536;
    u16* xg_wr = xg + (size_t)((ch + 1) & 1) * TC * 65536;
    int gblocks = (ch + 1 < nch) ? TC / 8 : 0;
    scan1_gemm<<<16 + gblocks, 1024, 0, stream>>>(
        whh1f, whh1b, xg_rd, xg_wr, wih1f, wih1b, bias1, f0, r0, lengths,
        cstate, hstate, pacc, hfeat, ffw, ch * TC, (ch + 1) * TC, (ch + 1) * TC, TC);
  }
  final_k<<<64, 64, 0, stream>>>(pcavg, hfeat, lw, lb, ffw, d_out);
}

// Round 10
// 2437.384 us; speedup vs baseline: 1.7505x; 1.7505x over previous
//
#include <hip/hip_runtime.h>

using u16 = unsigned short;
using u32 = unsigned int;

typedef __attribute__((ext_vector_type(8))) short bf16x8;
typedef __attribute__((ext_vector_type(4))) float f32x4;

#define L2E 1.44269504f

__device__ __forceinline__ float bf2f(u16 u) {
  union { u32 i; float f; } v; v.i = ((u32)u) << 16; return v.f;
}
__device__ __forceinline__ u16 f2bf(float f) {
  union { float f; u32 i; } v; v.f = f;
  u32 i = v.i;
  return (u16)((i + 0x7FFFu + ((i >> 16) & 1u)) >> 16);
}
__device__ __forceinline__ float fexp2(float x) { float r; asm("v_exp_f32 %0, %1" : "=v"(r) : "v"(x)); return r; }
__device__ __forceinline__ float frcp(float x) { float r; asm("v_rcp_f32 %0, %1" : "=v"(r) : "v"(x)); return r; }
__device__ __forceinline__ float sig_s(float xp) { return frcp(1.0f + fexp2(-xp)); }      // x pre-scaled by log2e
__device__ __forceinline__ float tanh_s(float x2) { return fmaf(-2.0f, frcp(1.0f + fexp2(x2)), 1.0f); } // x pre-scaled by 2log2e

__device__ __forceinline__ void barrier_lgkm() {
  asm volatile("s_waitcnt lgkmcnt(0)\n\ts_barrier" ::: "memory");
}

__device__ __forceinline__ float ldin(const void* p, long i, int f32) {
  return f32 ? ((const float*)p)[i] : bf2f(((const u16*)p)[i]);
}
__device__ __forceinline__ bf16x8 ldfrag(const void* p, long i, int f32) {
  if (!f32) return *(const bf16x8*)((const u16*)p + i);
  const float* f = (const float*)p + i;
  bf16x8 r;
#pragma unroll
  for (int j = 0; j < 8; ++j) r[j] = (short)f2bf(f[j]);
  return r;
}
__device__ __forceinline__ bf16x8 ldfrag_s(const void* p, long i, int f32, float s) {
  bf16x8 r;
  if (!f32) {
    const u16* h = (const u16*)p + i;
#pragma unroll
    for (int j = 0; j < 8; ++j) r[j] = (short)f2bf(bf2f(h[j]) * s);
  } else {
    const float* f = (const float*)p + i;
#pragma unroll
    for (int j = 0; j < 8; ++j) r[j] = (short)f2bf(f[j] * s);
  }
  return r;
}
__device__ __forceinline__ uint2 ld4(const void* p, long i, int f32) {
  if (!f32) return *(const uint2*)((const u16*)p + i);
  const float* f = (const float*)p + i;
  return make_uint2((u32)f2bf(f[0]) | ((u32)f2bf(f[1]) << 16),
                    (u32)f2bf(f[2]) | ((u32)f2bf(f[3]) << 16));
}

// inline dtype probe: ff_w ~ N(0,0.05^2) -> bf16 decodes all sane; f32-as-u16 doesn't
__device__ __forceinline__ int dtype_probe(const void* ffw) {
  const u16* h = (const u16*)ffw;
  int sane = 0;
  for (int i = 0; i < 64; ++i) {
    float v = bf2f(h[i]);
    sane += (v == v && fabsf(v) <= 1.0f) ? 1 : 0;
  }
  return (sane >= 60) ? 0 : 1;
}

// ---------------- prep: rank-1 layer0 terms + biases, pre-scaled by per-gate log2e ----------------
__global__ void prep_k(const void* ffw, const void* ffb,
                       const void* wih0f, const void* bih0f, const void* bhh0f,
                       const void* wih0b, const void* bih0b, const void* bhh0b,
                       const void* bih1f, const void* bhh1f,
                       const void* bih1b, const void* bhh1b,
                       float* __restrict__ prep0, float* __restrict__ bias1) {
  const int f32 = dtype_probe(ffw);
  int dir = blockIdx.x, r = threadIdx.x;
  const void* wih  = dir ? wih0b : wih0f;
  const void* bih0 = dir ? bih0b : bih0f;
  const void* bhh0 = dir ? bhh0b : bhh0f;
  const void* bih1 = dir ? bih1b : bih1f;
  const void* bhh1 = dir ? bhh1b : bhh1f;
  float u = 0.f, v = 0.f;
  for (int k = 0; k < 128; ++k) {
    float wv = ldin(wih, r * 128 + k, f32);
    u += wv * ldin(ffw, k, f32);
    v += wv * ldin(ffb, k, f32);
  }
  const float sc = ((r >> 7) == 2) ? 2.0f * L2E : L2E;
  float bi = ldin(bih0, r, f32) + ldin(bhh0, r, f32);
  prep0[dir * 1536 + r]        = u * sc;
  prep0[dir * 1536 + 512 + r]  = (bi + v) * sc;
  prep0[dir * 1536 + 1024 + r] = bi * sc;
  bias1[dir * 512 + r] = (ldin(bih1, r, f32) + ldin(bhh1, r, f32)) * sc;
}

// ---------------- conv body ----------------
__device__ void conv_body(int blk, int tid, const void* x,
                          const void* cw0, const void* cb0, const void* cw1, const void* cb1,
                          const void* cw2, const void* cb2, const void* cw3, const void* cb3,
                          int f32, float* __restrict__ pcavg) {
  int b = blk >> 3, ck = blk & 7;
  int P = ck * 255;
  __shared__ float xs[264];
  __shared__ float c1s[4][264];
  __shared__ float c2s[8][264];
  __shared__ float w0s[12], w1s[96], w2s[384], w3s[4608];
  __shared__ float b0s[4], b1s[8], b2s[16], b3s[96];
  __shared__ float red[8][96];
  for (int i = tid; i < 263; i += 512) xs[i] = ldin(x, (long)b * 2048 + P + i, f32);
  for (int i = tid; i < 12; i += 512) w0s[i] = ldin(cw0, i, f32);
  for (int i = tid; i < 96; i += 512) w1s[i] = ldin(cw1, i, f32);
  for (int i = tid; i < 384; i += 512) w2s[i] = ldin(cw2, i, f32);
  for (int i = tid; i < 4608; i += 512) w3s[i] = ldin(cw3, i, f32);
  if (tid < 4) b0s[tid] = ldin(cb0, tid, f32);
  if (tid < 8) b1s[tid] = ldin(cb1, tid, f32);
  if (tid < 16) b2s[tid] = ldin(cb2, tid, f32);
  if (tid < 96) b3s[tid] = ldin(cb3, tid, f32);
  __syncthreads();
  for (int i = tid; i < 4 * 261; i += 512) {
    int ch = i / 261, t = i % 261;
    float s = b0s[ch];
#pragma unroll
    for (int d = 0; d < 3; ++d) s += w0s[ch * 3 + d] * xs[t + d];
    c1s[ch][t] = fmaxf(s, 0.f);
  }
  __syncthreads();
  for (int i = tid; i < 8 * 259; i += 512) {
    int ch = i / 259, t = i % 259;
    float s = b1s[ch];
    for (int ic = 0; ic < 4; ++ic)
#pragma unroll
      for (int d = 0; d < 3; ++d) s += w1s[(ch * 4 + ic) * 3 + d] * c1s[ic][t + d];
    c2s[ch][t] = fmaxf(s, 0.f);
  }
  __syncthreads();
  const bool act = tid < 255;
  float c3w[16][3];
#pragma unroll
  for (int m = 0; m < 16; ++m)
#pragma unroll
    for (int dt = 0; dt < 3; ++dt) c3w[m][dt] = 0.f;
  if (act) {
#pragma unroll
    for (int m = 0; m < 16; ++m)
#pragma unroll
      for (int dt = 0; dt < 3; ++dt) {
        float s = b2s[m];
        for (int ic = 0; ic < 8; ++ic)
#pragma unroll
          for (int d = 0; d < 3; ++d) s += w2s[(m * 8 + ic) * 3 + d] * c2s[ic][tid + dt + d];
        c3w[m][dt] = fmaxf(s, 0.f);
      }
  }
  int wv = tid >> 6, lane = tid & 63;
  for (int o = 0; o < 96; ++o) {
    float s = b3s[o];
#pragma unroll
    for (int m = 0; m < 16; ++m)
#pragma unroll
      for (int dt = 0; dt < 3; ++dt) s += w3s[(o * 16 + m) * 3 + dt] * c3w[m][dt];
    float v = act ? fmaxf(s, 0.f) : 0.f;
    for (int off = 32; off > 0; off >>= 1) v += __shfl_down(v, off, 64);
    if (lane == 0) red[wv][o] = v;
  }
  __syncthreads();
  if (tid < 96) {
    float s = 0.f;
#pragma unroll
    for (int k = 0; k < 8; ++k) s += red[k][tid];
    pcavg[(size_t)(b * 8 + ck) * 96 + tid] = s;
  }
}

// ---------------- layer-1 input GEMM body ----------------
__device__ void xg_gemm_body(int bi, int tid,
                             const void* wih1f, const void* wih1b,
                             const float* __restrict__ bias1,
                             const u16* __restrict__ f0, const u16* __restrict__ r0,
                             const int* __restrict__ lengths,
                             u16* __restrict__ xg_wr, int ct0, int tc, int f32) {
  const int TCB = 32;
  int nt = tc / TCB;
  int dir = bi / (4 * nt);
  int rem = bi % (4 * nt);
  int g = rem / nt, tcb = rem % nt;
  int tstart = ct0 + tcb * TCB;
  const int w = tid >> 6, lane = tid & 63, q = lane >> 4, col = lane & 15;

  const void* wih = dir ? wih1b : wih1f;
  bf16x8 af[4][8];
#pragma unroll
  for (int gt = 0; gt < 4; ++gt)
#pragma unroll
    for (int kt = 0; kt < 8; ++kt)
      af[gt][kt] = ldfrag(wih, (long)(gt * 128 + w * 16 + col) * 256 + kt * 32 + q * 8, f32);
  f32x4 bias4[4];
#pragma unroll
  for (int gt = 0; gt < 4; ++gt)
    bias4[gt] = *(const f32x4*)(bias1 + dir * 512 + gt * 128 + w * 16 + q * 4);

  __shared__ u16 bin[2][16][264];
  int sb = tid >> 5, sk = (tid & 31) * 8;
  int gb = g * 16 + sb;
  int len_s = lengths[gb];

  auto stage = [&](int t, int buf) {
    uint4 v = make_uint4(0u, 0u, 0u, 0u);
    if (t < len_s) {
      int qt = len_s - 1 - t; if (qt < 0) qt = 0;
      int th0 = dir ? qt : t;
      int th1 = dir ? t : qt;
      if (sk < 128)
        v = *(const uint4*)(f0 + ((size_t)th0 * 64 + gb) * 128 + sk);
      else
        v = *(const uint4*)(r0 + ((size_t)th1 * 64 + gb) * 128 + sk - 128);
    }
    *(uint4*)&bin[buf][sb][sk] = v;
  };
  stage(tstart, 0);
  const int bglob = g * 16 + col;
  const int G4o = bglob >> 2, c4g = bglob & 3;
  for (int i = 0; i < TCB; ++i) {
    int t = tstart + i, buf = i & 1;
    barrier_lgkm();
    if (i + 1 < TCB) stage(t + 1, buf ^ 1);
    bf16x8 bfr[8];
#pragma unroll
    for (int kt = 0; kt < 8; ++kt) bfr[kt] = *(const bf16x8*)(&bin[buf][col][kt * 32 + q * 8]);
    f32x4 acc[4];
#pragma unroll
    for (int gt = 0; gt < 4; ++gt) acc[gt] = (f32x4){0.f, 0.f, 0.f, 0.f};
#pragma unroll
    for (int kt = 0; kt < 8; ++kt)
#pragma unroll
      for (int gt = 0; gt < 4; ++gt)
        acc[gt] = __builtin_amdgcn_mfma_f32_16x16x32_bf16(af[gt][kt], bfr[kt], acc[gt], 0, 0, 0);
    size_t eb = ((((size_t)(t - ct0) * 2 + dir) * 16 + G4o) * 8 + w) * 256 + q * 64 + c4g * 4;
#pragma unroll
    for (int gt = 0; gt < 4; ++gt) {
      float sgt = (gt == 2) ? 2.0f * L2E : L2E;
#pragma unroll
      for (int r = 0; r < 4; ++r)
        xg_wr[eb + r * 16 + gt] = f2bf(fmaf(acc[gt][r], sgt, bias4[gt][r]));
    }
  }
}

// ---------------- fused: L0 scan (blocks 0..31) + conv (blocks 32..543) ----------------
__global__ __launch_bounds__(512, 2) void scan0_conv(
    const void* whhf, const void* whhb,
    const void* x, const float* __restrict__ prep0,
    const int* __restrict__ lengths,
    u16* __restrict__ outf, u16* __restrict__ outr,
    const void* cw0, const void* cb0, const void* cw1, const void* cb1,
    const void* cw2, const void* cb2, const void* cw3, const void* cb3,
    float* __restrict__ pcavg, const void* ffw) {
  const int f32 = dtype_probe(ffw);
  const int tid = threadIdx.x;
  if (blockIdx.x >= 32) {
    conv_body(blockIdx.x - 32, tid, x, cw0, cb0, cw1, cb1, cw2, cb2, cw3, cb3, f32, pcavg);
    return;
  }
  const int blk = blockIdx.x;
  const int dir = blk >> 4, G4 = blk & 15;
  const int w = tid >> 6, lane = tid & 63, q = lane >> 4, col = lane & 15;
  const int c4 = lane & 3, uu_ = lane >> 2;
  const int unit = w * 16 + uu_;
  const int b = G4 * 4 + c4;
  const bool jb1 = ((lane >> 2) & 1) != 0;
  const bool jb2 = ((lane >> 2) & 2) != 0;

  __shared__ u16 hbuf[2][4][160];
  __shared__ u16 xls[4 * 2056];

  const void* whh = dir ? whhb : whhf;
  bf16x8 afr[4][4];
#pragma unroll
  for (int gt = 0; gt < 4; ++gt) {
    float sgt = (gt == 2) ? 2.0f * L2E : L2E;
#pragma unroll
    for (int kt = 0; kt < 4; ++kt)
      afr[gt][kt] = ldfrag_s(whh, (long)(gt * 128 + w * 16 + col) * 128 + kt * 32 + q * 8, f32, sgt);
  }

  float uuc[4], ppc[4], bbc[4];
  {
    const float* pr = prep0 + dir * 1536;
#pragma unroll
    for (int gt = 0; gt < 4; ++gt) {
      int rb = gt * 128 + unit;
      uuc[gt] = pr[rb];
      ppc[gt] = pr[512 + rb];
      bbc[gt] = pr[1024 + rb];
    }
  }
  const int len_c = lengths[b];
  const int lm1 = dir ? (len_c - 1) : 0;
  const int sgn = dir ? -1 : 1;

  float cst = 0.f;
  hbuf[0][c4][unit] = 0; hbuf[1][c4][unit] = 0;
  for (int i = tid; i < 4 * 512; i += 512) {
    int row = i >> 9, t4 = (i & 511) * 4;
    *(uint2*)&xls[row * 2056 + t4] = ld4(x, (long)(G4 * 4 + row) * 2048 + t4, f32);
  }
  __syncthreads();

  auto mkpre = [&](int t, float* pre) {
    int tb = lm1 + sgn * t;           // dir0: t; dir1: len-1-t
    tb = tb < 0 ? 0 : tb;             // dir0 t=2048 reads in-array pad; discarded via valid
    float xv = bf2f(xls[c4 * 2056 + tb]);
    bool valid = t < len_c;
    float xvv = valid ? xv : 0.f;
#pragma unroll
    for (int gt = 0; gt < 4; ++gt)
      pre[gt] = fmaf(xvv, uuc[gt], valid ? ppc[gt] : bbc[gt]);
  };
  float pre[4];
  mkpre(0, pre);

  int p = 0;
  u16* outp = (dir ? outr : outf) + (size_t)b * 128 + unit;   // advance 8192/step
  for (int t = 0; t < 2048; ++t) {
    bf16x8 bfr[4];
#pragma unroll
    for (int kt = 0; kt < 4; ++kt) bfr[kt] = *(const bf16x8*)(&hbuf[p][col & 3][kt * 32 + q * 8]);

    f32x4 acc[4];
#pragma unroll
    for (int gt = 0; gt < 4; ++gt) acc[gt] = (f32x4){0.f, 0.f, 0.f, 0.f};
#pragma unroll
    for (int kt = 0; kt < 4; ++kt)
#pragma unroll
      for (int gt = 0; gt < 4; ++gt)
        acc[gt] = __builtin_amdgcn_mfma_f32_16x16x32_bf16(afr[gt][kt], bfr[kt], acc[gt], 0, 0, 0);

    float gv[4];
#pragma unroll
    for (int gt = 0; gt < 4; ++gt) {
      float a = jb2 ? acc[gt][2] : acc[gt][0];
      float c = jb2 ? acc[gt][3] : acc[gt][1];
      gv[gt] = (jb1 ? c : a) + pre[gt];
    }

    float sf = sig_s(gv[1]);
    float si = sig_s(gv[0]);
    float tg = tanh_s(gv[2]);
    float so = sig_s(gv[3]);
    float cs = fmaf(sf, cst, si * tg);
    cst = cs;
    float hv = so * tanh_s(cs * (2.0f * L2E));
    u16 hb = f2bf(hv);
    hbuf[p ^ 1][c4][unit] = hb;
    *outp = hb;
    outp += 8192;
    mkpre(t + 1, pre);
    barrier_lgkm();
    p ^= 1;
  }
}

// ---------------- fused: L1 scan chunk (blocks 0..31) + xg_gemm for NEXT chunk ----------------
__global__ __launch_bounds__(512, 2) void scan1_gemm(
    const void* whhf, const void* whhb,
    const u16* __restrict__ xg_rd, u16* __restrict__ xg_wr,
    const void* wih1f, const void* wih1b, const float* __restrict__ bias1,
    const u16* __restrict__ f0, const u16* __restrict__ r0,
    const int* __restrict__ lengths,
    float* __restrict__ cstate, u16* __restrict__ hstate,
    float* __restrict__ pacc, float* __restrict__ hfeat,
    const void* ffw, int t0, int t1, int gct0, int TCc) {
  const int f32 = dtype_probe(ffw);
  const int tid = threadIdx.x;
  if (blockIdx.x >= 32) {
    xg_gemm_body(blockIdx.x - 32, tid, wih1f, wih1b, bias1, f0, r0, lengths,
                 xg_wr, gct0, TCc, f32);
    return;
  }
  const int blk = blockIdx.x;
  const int dir = blk >> 4, G4 = blk & 15;
  const int w = tid >> 6, lane = tid & 63, q = lane >> 4, col = lane & 15;
  const int c4 = lane & 3, uu_ = lane >> 2;
  const int unit = w * 16 + uu_;
  const int b = G4 * 4 + c4;
  const bool jb1 = ((lane >> 2) & 1) != 0;
  const bool jb2 = ((lane >> 2) & 2) != 0;

  __shared__ u16 hbuf[2][4][160];

  const void* whh = dir ? whhb : whhf;
  bf16x8 afr[4][4];
#pragma unroll
  for (int gt = 0; gt < 4; ++gt) {
    float sgt = (gt == 2) ? 2.0f * L2E : L2E;
#pragma unroll
    for (int kt = 0; kt < 4; ++kt)
      afr[gt][kt] = ldfrag_s(whh, (long)(gt * 128 + w * 16 + col) * 128 + kt * 32 + q * 8, f32, sgt);
  }
  const int len_c = lengths[b];
  const int lastt = dir ? 0 : (len_c - 1);

  int p = t0 & 1;
  float cst, psum, pmax, plast;
  if (t0 == 0) {
    cst = 0.f;
    hbuf[0][c4][unit] = 0; hbuf[1][c4][unit] = 0;
    psum = 0.f; pmax = -1e30f; plast = 0.f;
  } else {
    cst = cstate[blk * 512 + tid];
    hbuf[p][c4][unit] = hstate[blk * 512 + c4 * 128 + unit];
    long pb = (long)(blk * 512 + tid) * 4;
    psum = pacc[pb]; pmax = pacc[pb + 1]; plast = pacc[pb + 2];
  }
  __syncthreads();

  // xg pointer walks forward 65536 elements per step (affine for LSR)
  const u16* xgp = xg_rd + (((size_t)dir * 16 + G4) * 8 + w) * 256 + (size_t)lane * 4;
  float xf[4];
  auto unpack = [&](uint2 c, float* o) {
    o[0] = bf2f((u16)(c.x & 0xffffu));
    o[1] = bf2f((u16)(c.x >> 16));
    o[2] = bf2f((u16)(c.y & 0xffffu));
    o[3] = bf2f((u16)(c.y >> 16));
  };
  uint2 nxtA, nxtB;
  {
    uint2 c0 = *(const uint2*)xgp;
    unpack(c0, xf);
    nxtA = (t0 + 1 < t1) ? *(const uint2*)(xgp + 65536) : make_uint2(0, 0);
    nxtB = (t0 + 2 < t1) ? *(const uint2*)(xgp + 2 * 65536) : make_uint2(0, 0);
    xgp += (size_t)3 * 65536;
  }

  for (int t = t0; t < t1; ++t) {
    bf16x8 bfr[4];
#pragma unroll
    for (int kt = 0; kt < 4; ++kt) bfr[kt] = *(const bf16x8*)(&hbuf[p][col & 3][kt * 32 + q * 8]);

    f32x4 acc[4];
#pragma unroll
    for (int gt = 0; gt < 4; ++gt) acc[gt] = (f32x4){0.f, 0.f, 0.f, 0.f};
#pragma unroll
    for (int kt = 0; kt < 4; ++kt)
#pragma unroll
      for (int gt = 0; gt < 4; ++gt)
        acc[gt] = __builtin_amdgcn_mfma_f32_16x16x32_bf16(afr[gt][kt], bfr[kt], acc[gt], 0, 0, 0);

    float gv[4];
#pragma unroll
    for (int gt = 0; gt < 4; ++gt) {
      float a = jb2 ? acc[gt][2] : acc[gt][0];
      float c = jb2 ? acc[gt][3] : acc[gt][1];
      gv[gt] = (jb1 ? c : a) + xf[gt];
    }

    float sf = sig_s(gv[1]);
    float si = sig_s(gv[0]);
    float tg = tanh_s(gv[2]);
    float so = sig_s(gv[3]);
    float cs = fmaf(sf, cst, si * tg);
    cst = cs;
    float hv = so * tanh_s(cs * (2.0f * L2E));
    u16 hb = f2bf(hv);
    hbuf[p ^ 1][c4][unit] = hb;
    bool inlen = t < len_c;
    psum += inlen ? hv : 0.f;
    pmax = fmaxf(pmax, inlen ? hv : -1e30f);
    plast = (t == lastt) ? hv : plast;
    // rotate xg pipeline (off critical chain)
    unpack(nxtA, xf);
    nxtA = nxtB;
    if (t + 3 < t1) nxtB = *(const uint2*)xgp;
    xgp += 65536;
    barrier_lgkm();
    p ^= 1;
  }

  cstate[blk * 512 + tid] = cst;
  hstate[blk * 512 + c4 * 128 + unit] = hbuf[p][c4][unit];
  {
    long pb = (long)(blk * 512 + tid) * 4;
    pacc[pb] = psum; pacc[pb + 1] = pmax; pacc[pb + 2] = plast;
  }
  if (t1 == 2048) {
    int base = b * 768 + dir * 128 + unit;
    hfeat[base]       = psum / (float)len_c;
    hfeat[base + 256] = pmax;
    hfeat[base + 512] = plast;
  }
}

// ---------------- standalone first xg_gemm ----------------
__global__ __launch_bounds__(512, 2) void xg_gemm0(
    const void* wih1f, const void* wih1b, const float* __restrict__ bias1,
    const u16* __restrict__ f0, const u16* __restrict__ r0,
    const int* __restrict__ lengths,
    u16* __restrict__ xg_wr, const void* ffw, int ct0, int tc) {
  xg_gemm_body(blockIdx.x, threadIdx.x, wih1f, wih1b, bias1, f0, r0, lengths,
               xg_wr, ct0, tc, dtype_probe(ffw));
}

// ---------------- final linear ----------------
__global__ void final_k(const float* __restrict__ pcavg, const float* __restrict__ hfeat,
                        const void* lw, const void* lb,
                        const void* ffw, void* outv) {
  const int f32 = dtype_probe(ffw);
  int b = blockIdx.x, tid = threadIdx.x;
  float p0 = 0.f, p1 = 0.f, p2 = 0.f, p3 = 0.f;
  for (int k = tid; k < 864; k += 64) {
    float f;
    if (k < 96) {
      float s = 0.f;
#pragma unroll
      for (int c = 0; c < 8; ++c) s += pcavg[(size_t)(b * 8 + c) * 96 + k];
      f = s / 2040.f;
    } else {
      f = hfeat[b * 768 + k - 96];
    }
    p0 += f * ldin(lw, k, f32);
    p1 += f * ldin(lw, 864 + k, f32);
    p2 += f * ldin(lw, 2 * 864 + k, f32);
    p3 += f * ldin(lw, 3 * 864 + k, f32);
  }
  for (int off = 32; off > 0; off >>= 1) {
    p0 += __shfl_down(p0, off, 64);
    p1 += __shfl_down(p1, off, 64);
    p2 += __shfl_down(p2, off, 64);
    p3 += __shfl_down(p3, off, 64);
  }
  if (tid == 0) {
    float v0 = p0 + ldin(lb, 0, f32), v1 = p1 + ldin(lb, 1, f32);
    float v2 = p2 + ldin(lb, 2, f32), v3 = p3 + ldin(lb, 3, f32);
    if (f32) {
      float* o = (float*)outv;
      o[b * 4 + 0] = v0; o[b * 4 + 1] = v1; o[b * 4 + 2] = v2; o[b * 4 + 3] = v3;
    } else {
      u16* o = (u16*)outv;
      o[b * 4 + 0] = f2bf(v0); o[b * 4 + 1] = f2bf(v1);
      o[b * 4 + 2] = f2bf(v2); o[b * 4 + 3] = f2bf(v3);
    }
  }
}

extern "C" void kernel_launch(void* const* d_in, const int* in_sizes, int n_in,
                              void* d_out, int out_size, void* d_ws, size_t ws_size,
                              hipStream_t stream) {
  const void* x      = d_in[0];
  const int* lengths = (const int*)d_in[1];
  const void* ffw = d_in[2];
  const void* ffb = d_in[3];
  const void* wih0f = d_in[4];  const void* whh0f = d_in[5];
  const void* bih0f = d_in[6];  const void* bhh0f = d_in[7];
  const void* wih0b = d_in[8];  const void* whh0b = d_in[9];
  const void* bih0b = d_in[10]; const void* bhh0b = d_in[11];
  const void* wih1f = d_in[12]; const void* whh1f = d_in[13];
  const void* bih1f = d_in[14]; const void* bhh1f = d_in[15];
  const void* wih1b = d_in[16]; const void* whh1b = d_in[17];
  const void* bih1b = d_in[18]; const void* bhh1b = d_in[19];
  const void* cw0 = d_in[20]; const void* cb0 = d_in[21];
  const void* cw1 = d_in[22]; const void* cb1 = d_in[23];
  const void* cw2 = d_in[24]; const void* cb2 = d_in[25];
  const void* cw3 = d_in[26]; const void* cb3 = d_in[27];
  const void* lw = d_in[28];  const void* lb = d_in[29];

  float* prep0  = (float*)d_ws + 16;
  float* bias1  = prep0 + 3072;
  float* pcavg  = bias1 + 1024;
  float* hfeat  = pcavg + 49152;
  float* cstate = hfeat + 49152;
  float* pacc   = cstate + 16384;
  u16* f0 = (u16*)(pacc + 65536);
  const size_t SEQ = (size_t)2048 * 64 * 128;
  u16* r0 = f0 + SEQ;
  u16* hstate = r0 + SEQ;
  u16* xg = hstate + 16384;

  size_t base_bytes = (size_t)((char*)xg - (char*)d_ws);
  int TC = 32;
  for (int cand = 512; cand >= 32; cand >>= 1)
    if (ws_size >= base_bytes + (size_t)2 * cand * 65536 * 2) { TC = cand; break; }

  prep_k<<<2, 512, 0, stream>>>(ffw, ffb, wih0f, bih0f, bhh0f, wih0b, bih0b, bhh0b,
                                bih1f, bhh1f, bih1b, bhh1b, prep0, bias1);
  scan0_conv<<<544, 512, 0, stream>>>(whh0f, whh0b, x, prep0, lengths, f0, r0,
                                      cw0, cb0, cw1, cb1, cw2, cb2, cw3, cb3,
                                      pcavg, ffw);
  const int nch = 2048 / TC;
  xg_gemm0<<<TC / 4, 512, 0, stream>>>(wih1f, wih1b, bias1, f0, r0, lengths,
                                       xg, ffw, 0, TC);
  for (int ch = 0; ch < nch; ++ch) {
    u16* xg_rd = xg + (size_t)(ch & 1) * TC * 65536;
    u16* xg_wr = xg + (size_t)((ch + 1) & 1) * TC * 65536;
    int gblocks = (ch + 1 < nch) ? TC / 4 : 0;
    scan1_gemm<<<32 + gblocks, 512, 0, stream>>>(
        whh1f, whh1b, xg_rd, xg_wr, wih1f, wih1b, bias1, f0, r0, lengths,
        cstate, hstate, pacc, hfeat, ffw, ch * TC, (ch + 1) * TC, (ch + 1) * TC, TC);
  }
  final_k<<<64, 64, 0, stream>>>(pcavg, hfeat, lw, lb, ffw, d_out);
}